// Round 9
// baseline (65.749 us; speedup 1.0000x reference)
//
#include <hip/hip_runtime.h>
#include <cstddef>
#include <cstdint>

typedef __attribute__((ext_vector_type(8))) short bf16x8;
typedef __attribute__((ext_vector_type(4))) unsigned short ushort4v;
typedef __attribute__((ext_vector_type(8))) unsigned short ushort8v;
typedef __attribute__((ext_vector_type(16))) float f32x16;

__device__ __forceinline__ unsigned short f2bf(float f) {
  union { float f; unsigned u; } v; v.f = f;
  unsigned r = v.u + 0x7FFFu + ((v.u >> 16) & 1u);  // round-to-nearest-even
  return (unsigned short)(r >> 16);
}

// async global->LDS, 16B per lane; dest = wave-uniform base + lane*16
__device__ __forceinline__ void gload16(const void* g, void* l) {
  __builtin_amdgcn_global_load_lds(
      (const __attribute__((address_space(1))) void*)(unsigned long long)(uintptr_t)g,
      (__attribute__((address_space(3))) void*)(unsigned)(uintptr_t)l, 16, 0, 0);
}

// ---------------- stage 1: x -> bf16 channel-last (zero-padded) + gap partials
// grid = 4096 blocks ((b,g,row-pair)), 256 threads.
// xt layout: [b][g][66 row][66 col][32 ic] bf16, 1-px zero halo.
#define PADC 132
__global__ __launch_bounds__(256) void prep_kernel(
    const float* __restrict__ x, unsigned short* __restrict__ xt,
    float* __restrict__ partials) {
  __shared__ unsigned short cm[32 * PADC];  // channel-major bf16: [ic][128 px]
  __shared__ float sred[32][32];
  const int bid = blockIdx.x;
  // XCD-chunked: xt[bg] written on XCD bg>>4 (matches conv reader)
  const int wkr = ((bid & 7) << 9) | (bid >> 3);
  const int yp = wkr & 31, g = (wkr >> 5) & 7, b = wkr >> 8;
  const int y0 = yp * 2;
  const int tid = threadIdx.x;
  const float* xg = x + (size_t)(b * 256 + g * 32) * 4096;

  float csum[4];
#pragma unroll
  for (int j = 0; j < 4; ++j) {
    const int idx = tid + 256 * j;
    const int ic = idx >> 5;  // 0..31
    const int r = idx & 31;
    const int ry = r >> 4, gx4 = (r & 15) * 4;
    const float4 v = *reinterpret_cast<const float4*>(
        xg + (size_t)ic * 4096 + (y0 + ry) * 64 + gx4);
    csum[j] = v.x + v.y + v.z + v.w;
    ushort4v s;
    s[0] = f2bf(v.x); s[1] = f2bf(v.y); s[2] = f2bf(v.z); s[3] = f2bf(v.w);
    *reinterpret_cast<ushort4v*>(&cm[ic * PADC + ry * 64 + gx4]) = s;
  }
#pragma unroll
  for (int j = 0; j < 4; ++j) {
    const int ic = (tid >> 5) + 8 * j;
    sred[ic][tid & 31] = csum[j];
  }
  __syncthreads();

  if (tid < 32) {
    float s = 0.f;
#pragma unroll
    for (int i = 0; i < 32; ++i) s += sred[tid][i];
    partials[(size_t)(b * 256 + g * 32 + tid) * 32 + yp] = s;
  }

  const size_t xtb = (size_t)(b * 8 + g) * (66 * 66 * 32);
#pragma unroll
  for (int jj = 0; jj < 2; ++jj) {
    const int o = tid + 256 * jj;  // 0..511
    const int px = o >> 2, icq = o & 3;
    const int ry = px >> 6, gx = px & 63;
    ushort8v t;
#pragma unroll
    for (int c2 = 0; c2 < 8; ++c2) t[c2] = cm[(icq * 8 + c2) * PADC + px];
    *reinterpret_cast<ushort8v*>(
        &xt[xtb + ((size_t)(y0 + ry + 1) * 66 + (gx + 1)) * 32 + icq * 8]) = t;
  }

  const ushort8v z = {0, 0, 0, 0, 0, 0, 0, 0};
  if (tid < 16) {
    const int rr = tid >> 3;
    const int side = (tid >> 2) & 1;
    const int icq = tid & 3;
    const int col = side * 65;
    *reinterpret_cast<ushort8v*>(
        &xt[xtb + ((size_t)(y0 + rr + 1) * 66 + col) * 32 + icq * 8]) = z;
  }
  if (yp == 0 || yp == 31) {
    const int row = (yp == 0) ? 0 : 65;
    for (int o = tid; o < 66 * 4; o += 256) {
      const int col = o >> 2, icq = o & 3;
      *reinterpret_cast<ushort8v*>(
          &xt[xtb + ((size_t)row * 66 + col) * 32 + icq * 8]) = z;
    }
  }
}

// ---------------- stage 2: glgf generation, gate FOLDED into weights ----
// grid = 128 blocks, 256 threads. wpack[bg] holds (w * c) in A-frag order.
__global__ __launch_bounds__(256) void glgf_pack(
    const float* __restrict__ partials,
    const float* __restrict__ w1l, const float* __restrict__ w1g1,
    const float* __restrict__ w1g2, const float* __restrict__ w2l,
    const float* __restrict__ w2g,
    const float* __restrict__ v1l, const float* __restrict__ v1g1,
    const float* __restrict__ v1g2, const float* __restrict__ v2l,
    const float* __restrict__ v2g,
    unsigned short* __restrict__ wpack) {
  __shared__ float gapL[256];
  __shared__ float t1L[16];
  __shared__ float h1L[256];
  __shared__ float red[256];
  __shared__ float cLs[32];
  const int bid = blockIdx.x;
  const int bg = ((bid & 7) << 4) | (bid >> 3);  // block on XCD bg>>4
  const int g = bg & 7, b = bg >> 3;
  const int c = threadIdx.x;
  {
    float s = 0.f;
    const float* pp = partials + (size_t)(b * 256 + c) * 32;
#pragma unroll
    for (int i = 0; i < 32; ++i) s += pp[i];
    gapL[c] = s * (1.f / 4096.f);
  }
  __syncthreads();

  const int gbase = c & ~15;
  // ---- generator 1 ----
  float local1 = 0.f;
#pragma unroll
  for (int i = 0; i < 16; ++i) local1 += gapL[gbase + i] * w1l[c * 16 + i];
  if (c < 16) {
    float t = 0.f;
#pragma unroll
    for (int i = 0; i < 16; ++i) t += gapL[c * 16 + i] * w1g1[c * 16 + i];
    t1L[c] = t;
  }
  __syncthreads();
  float glob1 = 0.f;
#pragma unroll
  for (int gg = 0; gg < 16; ++gg) glob1 += t1L[gg] * w1g2[c * 16 + gg];
  const float h1 = 1.f / (1.f + expf(-(local1 + glob1)));
  h1L[c] = h1;
  red[c] = h1 * w2g[c];
  __syncthreads();
  for (int s = 128; s > 0; s >>= 1) {
    if (c < s) red[c] += red[c + s];
    __syncthreads();
  }
  const float glob2 = red[0];

  // ---- generator 2 (gate), computed in every block, folded into pack ----
  float local2 = 0.f;
#pragma unroll
  for (int i = 0; i < 16; ++i) local2 += gapL[gbase + i] * v1l[c * 16 + i];
  if (c < 16) {
    float t = 0.f;
#pragma unroll
    for (int i = 0; i < 16; ++i) t += gapL[c * 16 + i] * v1g1[c * 16 + i];
    t1L[c] = t;
  }
  __syncthreads();  // also separates red[0] reads from red reuse
  float glob1b = 0.f;
#pragma unroll
  for (int gg = 0; gg < 16; ++gg) glob1b += t1L[gg] * v1g2[c * 16 + gg];
  const float h2 = 1.f / (1.f + expf(-(local2 + glob1b)));
  red[c] = h2 * v2g[c];
  __syncthreads();
  for (int s = 128; s > 0; s >>= 1) {
    if (c < s) red[c] += red[c + s];
    __syncthreads();
  }
  if (c < 32) {
    const int o = g * 32 + c;
    const float h2o = 1.f / (1.f + expf(-(
        [&] { float l = 0.f;
#pragma unroll
              for (int i = 0; i < 16; ++i) l += gapL[(o & ~15) + i] * v1l[o * 16 + i];
              float gl = 0.f;
#pragma unroll
              for (int gg = 0; gg < 16; ++gg) gl += t1L[gg] * v1g2[o * 16 + gg];
              return l + gl; }())));
    cLs[c] = h2o * v2l[o] + red[0];
  }
  __syncthreads();

  // ---- pack (w * c) for this (b,g): A-fragment order ----
  unsigned short* wpo = wpack + (size_t)bg * 9216;
#pragma unroll 4
  for (int it = 0; it < 36; ++it) {
    const int idx = it * 256 + c;
    const int kk = idx >> 9;
    const int rem = idx & 511;
    const int l = rem >> 3, e = rem & 7;
    const int oc = l & 31, hi = l >> 5;
    const int ic = ((kk & 1) << 4) + hi * 8 + e;
    const int sp = kk >> 1;
    const int o = (g << 5) + oc;
    const float wv = h1L[o] * w2l[o * 288 + ic * 9 + sp] + glob2;
    wpo[idx] = f2bf(wv * cLs[oc]);
  }
}

// ---------------- stage 3: conv — A in VGPR, dbuf LDS via global_load_lds,
// counted-vmcnt raw barriers (one per p), per-p fire-and-forget stores ----
// grid = 1024 blocks ((b,g,yq)), 256 threads = 4 waves, 4 blocks/CU.
__global__ __launch_bounds__(256, 4) void conv_kernel(
    const unsigned short* __restrict__ wpack,
    const unsigned short* __restrict__ xt, float* __restrict__ out) {
  __shared__ __align__(16) unsigned short btile[2][8448];  // 2 x 16896 B

  const int bid = blockIdx.x;
  const int wkr = ((bid & 7) << 7) | (bid >> 3);  // XCD-chunked, bijective
  const int yq = wkr & 7;
  const int bg = wkr >> 3;
  const int g = bg & 7, b = bg >> 3;
  const int tid = threadIdx.x;
  const int lane = tid & 63, wave = tid >> 6;
  const int n = lane & 31, hi = lane >> 5;
  const int wr = wave >> 1, wc = wave & 1;

  const char* xbase = (const char*)xt + (size_t)bg * 278784;  // 66*66*32*2 B

  // ---- A fragments -> VGPR (gate pre-folded); 18 x b128 from L2 ----
  const unsigned short* wp = wpack + (size_t)bg * 9216 + lane * 8;
  bf16x8 a[18];
#pragma unroll
  for (int kk = 0; kk < 18; ++kk) {
    a[kk] = *reinterpret_cast<const bf16x8*>(wp + kk * 512);
    asm volatile("" : "+v"(a[kk]));  // pin in VGPRs
  }

  // staging source offsets: LDS slot c = i*256 + tid, linear dest,
  // inverse-swizzled source chunk cq = cqs ^ (px&3)  [rule #21 pattern]
  int s_boff[5];
#pragma unroll
  for (int i = 0; i < 5; ++i) {
    const int cc = (i * 256 + tid) < 1056 ? (i * 256 + tid) : 0;
    const int r = cc / 264, rem = cc % 264;
    const int cqs = rem / 66, px = rem % 66;
    const int cq = cqs ^ (px & 3);
    s_boff[i] = r * 4224 + px * 64 + cq * 16;  // bytes, before ys term
  }

  // prologue: stage tile 0 into side 0
  {
    const int yb = yq * 8 * 4224;
#pragma unroll
    for (int i = 0; i < 5; ++i)
      if (i * 256 + tid < 1056)
        gload16(xbase + yb + s_boff[i],
                (char*)&btile[0][0] + i * 4096 + wave * 1024);
  }
  asm volatile("s_waitcnt vmcnt(0) lgkmcnt(0)\n\ts_barrier" ::: "memory");
  __builtin_amdgcn_sched_barrier(0);

  float* ob0 = out + (size_t)(b * 256 + g * 32) * 4096 + wc * 32 + n +
               (size_t)(hi << 2) * 4096;

#pragma unroll
  for (int p = 0; p < 4; ++p) {
    const int side = p & 1;
    // prefetch tile p+1 into other side (completes under MFMA + next barrier)
    if (p < 3) {
      const int yb = (yq * 8 + (p + 1) * 2) * 4224;
#pragma unroll
      for (int i = 0; i < 5; ++i)
        if (i * 256 + tid < 1056)
          gload16(xbase + yb + s_boff[i],
                  (char*)&btile[side ^ 1][0] + i * 4096 + wave * 1024);
    }

    f32x16 acc;
#pragma unroll
    for (int i = 0; i < 16; ++i) acc[i] = 0.f;

    __builtin_amdgcn_s_setprio(1);
#pragma unroll
    for (int kk = 0; kk < 18; ++kk) {
      const int sp = kk >> 1;
      const int ky = sp / 3, kx = sp % 3;
      const int px2 = wc * 32 + n + kx;
      const int cq = ((kk & 1) << 1) + hi;
      const bf16x8 bf = *reinterpret_cast<const bf16x8*>(
          &btile[side][((((wr + ky) << 2) + (cq ^ (px2 & 3))) * 66 + px2) * 8]);
      acc = __builtin_amdgcn_mfma_f32_32x32x16_bf16(a[kk], bf, acc, 0, 0, 0);
    }
    __builtin_amdgcn_s_setprio(0);

    // stores: fire-and-forget; vmcnt(16) below leaves exactly these in flight
    const int y = yq * 8 + p * 2 + wr;
    float* ob = ob0 + y * 64;
#pragma unroll
    for (int r = 0; r < 16; ++r) {
      const int row = (r & 3) + ((r >> 2) << 3);  // hi-term folded into ob0
      ob[(size_t)row * 4096] = acc[r];
    }

    if (p < 3) {
      // drain gloads (older than the 16 stores), never drain the stores
      asm volatile("s_waitcnt vmcnt(16) lgkmcnt(0)\n\ts_barrier" ::: "memory");
      __builtin_amdgcn_sched_barrier(0);
    }
  }
}

extern "C" void kernel_launch(void* const* d_in, const int* in_sizes, int n_in,
                              void* d_out, int out_size, void* d_ws,
                              size_t ws_size, hipStream_t stream) {
  const float* x    = (const float*)d_in[0];
  const float* w1l  = (const float*)d_in[1];
  const float* w1g1 = (const float*)d_in[2];
  const float* w1g2 = (const float*)d_in[3];
  const float* w2l  = (const float*)d_in[4];
  const float* w2g  = (const float*)d_in[5];
  const float* v1l  = (const float*)d_in[6];
  const float* v1g1 = (const float*)d_in[7];
  const float* v1g2 = (const float*)d_in[8];
  const float* v2l  = (const float*)d_in[9];
  const float* v2g  = (const float*)d_in[10];
  float* out = (float*)d_out;

  unsigned short* xt = (unsigned short*)d_ws;      // 17,842,176 bf16
  float* partials = (float*)(xt + 17842176);       // 131,072 f32
  unsigned short* wpack = (unsigned short*)(partials + 131072);  // 1,179,648 bf16

  prep_kernel<<<4096, 256, 0, stream>>>(x, xt, partials);
  glgf_pack<<<128, 256, 0, stream>>>(partials, w1l, w1g1, w1g2, w2l, w2g,
                                     v1l, v1g1, v1g2, v2l, v2g, wpack);
  conv_kernel<<<1024, 256, 0, stream>>>(wpack, xt, out);
}

// Round 10
// 55.435 us; speedup vs baseline: 1.1860x; 1.1860x over previous
//
#include <hip/hip_runtime.h>
#include <cstddef>
#include <cstdint>

typedef __attribute__((ext_vector_type(8))) short bf16x8;
typedef __attribute__((ext_vector_type(4))) unsigned short ushort4v;
typedef __attribute__((ext_vector_type(8))) unsigned short ushort8v;
typedef __attribute__((ext_vector_type(16))) float f32x16;

__device__ __forceinline__ unsigned short f2bf(float f) {
  union { float f; unsigned u; } v; v.f = f;
  unsigned r = v.u + 0x7FFFu + ((v.u >> 16) & 1u);  // round-to-nearest-even
  return (unsigned short)(r >> 16);
}

// async global->LDS, 16B per lane; dest = wave-uniform base + lane*16
__device__ __forceinline__ void gload16(const void* g, void* l) {
  __builtin_amdgcn_global_load_lds(
      (const __attribute__((address_space(1))) void*)(unsigned long long)(uintptr_t)g,
      (__attribute__((address_space(3))) void*)(unsigned)(uintptr_t)l, 16, 0, 0);
}

// ---------------- stage 1: x -> bf16 channel-last (zero-padded) + gap partials
// grid = 4096 blocks ((b,g,row-pair)), 256 threads.
// xt layout: [b][g][66 row][66 col][32 ic] bf16, 1-px zero halo.
#define PADC 132
__global__ __launch_bounds__(256) void prep_kernel(
    const float* __restrict__ x, unsigned short* __restrict__ xt,
    float* __restrict__ partials) {
  __shared__ unsigned short cm[32 * PADC];  // channel-major bf16: [ic][128 px]
  __shared__ float sred[32][32];
  const int bid = blockIdx.x;
  // XCD-chunked: xt[bg] written on XCD bg>>4 (matches conv reader)
  const int wkr = ((bid & 7) << 9) | (bid >> 3);
  const int yp = wkr & 31, g = (wkr >> 5) & 7, b = wkr >> 8;
  const int y0 = yp * 2;
  const int tid = threadIdx.x;
  const float* xg = x + (size_t)(b * 256 + g * 32) * 4096;

  float csum[4];
#pragma unroll
  for (int j = 0; j < 4; ++j) {
    const int idx = tid + 256 * j;
    const int ic = idx >> 5;  // 0..31
    const int r = idx & 31;
    const int ry = r >> 4, gx4 = (r & 15) * 4;
    const float4 v = *reinterpret_cast<const float4*>(
        xg + (size_t)ic * 4096 + (y0 + ry) * 64 + gx4);
    csum[j] = v.x + v.y + v.z + v.w;
    ushort4v s;
    s[0] = f2bf(v.x); s[1] = f2bf(v.y); s[2] = f2bf(v.z); s[3] = f2bf(v.w);
    *reinterpret_cast<ushort4v*>(&cm[ic * PADC + ry * 64 + gx4]) = s;
  }
#pragma unroll
  for (int j = 0; j < 4; ++j) {
    const int ic = (tid >> 5) + 8 * j;
    sred[ic][tid & 31] = csum[j];
  }
  __syncthreads();

  if (tid < 32) {
    float s = 0.f;
#pragma unroll
    for (int i = 0; i < 32; ++i) s += sred[tid][i];
    partials[(size_t)(b * 256 + g * 32 + tid) * 32 + yp] = s;
  }

  const size_t xtb = (size_t)(b * 8 + g) * (66 * 66 * 32);
#pragma unroll
  for (int jj = 0; jj < 2; ++jj) {
    const int o = tid + 256 * jj;  // 0..511
    const int px = o >> 2, icq = o & 3;
    const int ry = px >> 6, gx = px & 63;
    ushort8v t;
#pragma unroll
    for (int c2 = 0; c2 < 8; ++c2) t[c2] = cm[(icq * 8 + c2) * PADC + px];
    *reinterpret_cast<ushort8v*>(
        &xt[xtb + ((size_t)(y0 + ry + 1) * 66 + (gx + 1)) * 32 + icq * 8]) = t;
  }

  const ushort8v z = {0, 0, 0, 0, 0, 0, 0, 0};
  if (tid < 16) {
    const int rr = tid >> 3;
    const int side = (tid >> 2) & 1;
    const int icq = tid & 3;
    const int col = side * 65;
    *reinterpret_cast<ushort8v*>(
        &xt[xtb + ((size_t)(y0 + rr + 1) * 66 + col) * 32 + icq * 8]) = z;
  }
  if (yp == 0 || yp == 31) {
    const int row = (yp == 0) ? 0 : 65;
    for (int o = tid; o < 66 * 4; o += 256) {
      const int col = o >> 2, icq = o & 3;
      *reinterpret_cast<ushort8v*>(
          &xt[xtb + ((size_t)row * 66 + col) * 32 + icq * 8]) = z;
    }
  }
}

// ---------------- stage 2: glgf generation, gate FOLDED into weights ----
// grid = 128 blocks, 256 threads. wpack[bg] holds (w * c) in A-frag order.
__global__ __launch_bounds__(256) void glgf_pack(
    const float* __restrict__ partials,
    const float* __restrict__ w1l, const float* __restrict__ w1g1,
    const float* __restrict__ w1g2, const float* __restrict__ w2l,
    const float* __restrict__ w2g,
    const float* __restrict__ v1l, const float* __restrict__ v1g1,
    const float* __restrict__ v1g2, const float* __restrict__ v2l,
    const float* __restrict__ v2g,
    unsigned short* __restrict__ wpack) {
  __shared__ float gapL[256];
  __shared__ float t1L[16];
  __shared__ float h1L[256];
  __shared__ float red[256];
  __shared__ float cLs[32];
  const int bid = blockIdx.x;
  const int bg = ((bid & 7) << 4) | (bid >> 3);  // block on XCD bg>>4
  const int g = bg & 7, b = bg >> 3;
  const int c = threadIdx.x;
  {
    float s = 0.f;
    const float* pp = partials + (size_t)(b * 256 + c) * 32;
#pragma unroll
    for (int i = 0; i < 32; ++i) s += pp[i];
    gapL[c] = s * (1.f / 4096.f);
  }
  __syncthreads();

  const int gbase = c & ~15;
  // ---- generator 1 ----
  float local1 = 0.f;
#pragma unroll
  for (int i = 0; i < 16; ++i) local1 += gapL[gbase + i] * w1l[c * 16 + i];
  if (c < 16) {
    float t = 0.f;
#pragma unroll
    for (int i = 0; i < 16; ++i) t += gapL[c * 16 + i] * w1g1[c * 16 + i];
    t1L[c] = t;
  }
  __syncthreads();
  float glob1 = 0.f;
#pragma unroll
  for (int gg = 0; gg < 16; ++gg) glob1 += t1L[gg] * w1g2[c * 16 + gg];
  const float h1 = 1.f / (1.f + expf(-(local1 + glob1)));
  h1L[c] = h1;
  red[c] = h1 * w2g[c];
  __syncthreads();
  for (int s = 128; s > 0; s >>= 1) {
    if (c < s) red[c] += red[c + s];
    __syncthreads();
  }
  const float glob2 = red[0];

  // ---- generator 2 (gate), folded into pack ----
  float local2 = 0.f;
#pragma unroll
  for (int i = 0; i < 16; ++i) local2 += gapL[gbase + i] * v1l[c * 16 + i];
  if (c < 16) {
    float t = 0.f;
#pragma unroll
    for (int i = 0; i < 16; ++i) t += gapL[c * 16 + i] * v1g1[c * 16 + i];
    t1L[c] = t;
  }
  __syncthreads();  // also separates red[0] reads from red reuse
  float glob1b = 0.f;
#pragma unroll
  for (int gg = 0; gg < 16; ++gg) glob1b += t1L[gg] * v1g2[c * 16 + gg];
  const float h2 = 1.f / (1.f + expf(-(local2 + glob1b)));
  red[c] = h2 * v2g[c];
  __syncthreads();
  for (int s = 128; s > 0; s >>= 1) {
    if (c < s) red[c] += red[c + s];
    __syncthreads();
  }
  if (c < 32) {
    const int o = g * 32 + c;
    float l = 0.f;
#pragma unroll
    for (int i = 0; i < 16; ++i) l += gapL[(o & ~15) + i] * v1l[o * 16 + i];
    float gl = 0.f;
#pragma unroll
    for (int gg = 0; gg < 16; ++gg) gl += t1L[gg] * v1g2[o * 16 + gg];
    const float h2o = 1.f / (1.f + expf(-(l + gl)));
    cLs[c] = h2o * v2l[o] + red[0];
  }
  __syncthreads();

  // ---- pack (w * c) for this (b,g): A-fragment order ----
  unsigned short* wpo = wpack + (size_t)bg * 9216;
#pragma unroll 4
  for (int it = 0; it < 36; ++it) {
    const int idx = it * 256 + c;
    const int kk = idx >> 9;
    const int rem = idx & 511;
    const int l = rem >> 3, e = rem & 7;
    const int oc = l & 31, hi = l >> 5;
    const int ic = ((kk & 1) << 4) + hi * 8 + e;
    const int sp = kk >> 1;
    const int o = (g << 5) + oc;
    const float wv = h1L[o] * w2l[o * 288 + ic * 9 + sp] + glob2;
    wpo[idx] = f2bf(wv * cLs[oc]);
  }
}

// ---------------- stage 3: conv — A in VGPR (cap 170 via waves/EU=3),
// dbuf LDS via global_load_lds, counted-vmcnt raw barriers, per-p stores ----
// grid = 1024 blocks ((b,g,yq)), 256 threads = 4 waves, 3 blocks/CU.
__global__ __launch_bounds__(256, 3) void conv_kernel(
    const unsigned short* __restrict__ wpack,
    const unsigned short* __restrict__ xt, float* __restrict__ out) {
  __shared__ __align__(16) unsigned short btile[2][8448];  // 2 x 16896 B

  const int bid = blockIdx.x;
  const int wkr = ((bid & 7) << 7) | (bid >> 3);  // XCD-chunked, bijective
  const int yq = wkr & 7;
  const int bg = wkr >> 3;
  const int g = bg & 7, b = bg >> 3;
  const int tid = threadIdx.x;
  const int lane = tid & 63, wave = tid >> 6;
  const int n = lane & 31, hi = lane >> 5;
  const int wr = wave >> 1, wc = wave & 1;

  const char* xbase = (const char*)xt + (size_t)bg * 278784;  // 66*66*32*2 B

  // staging source offsets: LDS slot c = i*256 + tid (linear dest),
  // inverse-swizzled source chunk cq = cqs ^ (px&3)  [rule #21 pattern]
  int s_boff[5];
#pragma unroll
  for (int i = 0; i < 5; ++i) {
    const int cc = (i * 256 + tid) < 1056 ? (i * 256 + tid) : 0;
    const int r = cc / 264, rem = cc % 264;
    const int cqs = rem / 66, px = rem % 66;
    const int cq = cqs ^ (px & 3);
    s_boff[i] = r * 4224 + px * 64 + cq * 16;  // bytes, before ys term
  }

  // ---- A fragments -> VGPR (gate pre-folded); 18 x b128 from L2 ----
  const unsigned short* wp = wpack + (size_t)bg * 9216 + lane * 8;
  bf16x8 a[18];
#pragma unroll
  for (int kk = 0; kk < 18; ++kk) {
    a[kk] = *reinterpret_cast<const bf16x8*>(wp + kk * 512);
    asm volatile("" : "+v"(a[kk]));  // keep in VGPRs (cap 170 fits ~116)
  }

  // prologue: stage tile 0 into side 0
  {
    const int yb = yq * 8 * 4224;
#pragma unroll
    for (int i = 0; i < 5; ++i)
      if (i * 256 + tid < 1056)
        gload16(xbase + yb + s_boff[i],
                (char*)&btile[0][0] + i * 4096 + wave * 1024);
  }
  asm volatile("s_waitcnt vmcnt(0) lgkmcnt(0)\n\ts_barrier" ::: "memory");
  __builtin_amdgcn_sched_barrier(0);

  float* ob0 = out + (size_t)(b * 256 + g * 32) * 4096 + wc * 32 + n +
               (size_t)(hi << 2) * 4096;

#pragma unroll
  for (int p = 0; p < 4; ++p) {
    const int side = p & 1;
    // prefetch tile p+1 into other side (completes under MFMA + next barrier)
    if (p < 3) {
      const int yb = (yq * 8 + (p + 1) * 2) * 4224;
#pragma unroll
      for (int i = 0; i < 5; ++i)
        if (i * 256 + tid < 1056)
          gload16(xbase + yb + s_boff[i],
                  (char*)&btile[side ^ 1][0] + i * 4096 + wave * 1024);
    }

    f32x16 acc;
#pragma unroll
    for (int i = 0; i < 16; ++i) acc[i] = 0.f;

    __builtin_amdgcn_s_setprio(1);
#pragma unroll
    for (int kk = 0; kk < 18; ++kk) {
      const int sp = kk >> 1;
      const int ky = sp / 3, kx = sp % 3;
      const int px2 = wc * 32 + n + kx;
      const int cq = ((kk & 1) << 1) + hi;
      const bf16x8 bf = *reinterpret_cast<const bf16x8*>(
          &btile[side][((((wr + ky) << 2) + (cq ^ (px2 & 3))) * 66 + px2) * 8]);
      acc = __builtin_amdgcn_mfma_f32_32x32x16_bf16(a[kk], bf, acc, 0, 0, 0);
    }
    __builtin_amdgcn_s_setprio(0);

    // stores: fire-and-forget; vmcnt(16) below leaves exactly these in flight
    const int y = yq * 8 + p * 2 + wr;
    float* ob = ob0 + y * 64;
#pragma unroll
    for (int r = 0; r < 16; ++r) {
      const int row = (r & 3) + ((r >> 2) << 3);  // hi-term folded into ob0
      ob[(size_t)row * 4096] = acc[r];
    }

    if (p < 3) {
      // drain gloads (older than the 16 stores), never drain the stores
      asm volatile("s_waitcnt vmcnt(16) lgkmcnt(0)\n\ts_barrier" ::: "memory");
      __builtin_amdgcn_sched_barrier(0);
    }
  }
}

extern "C" void kernel_launch(void* const* d_in, const int* in_sizes, int n_in,
                              void* d_out, int out_size, void* d_ws,
                              size_t ws_size, hipStream_t stream) {
  const float* x    = (const float*)d_in[0];
  const float* w1l  = (const float*)d_in[1];
  const float* w1g1 = (const float*)d_in[2];
  const float* w1g2 = (const float*)d_in[3];
  const float* w2l  = (const float*)d_in[4];
  const float* w2g  = (const float*)d_in[5];
  const float* v1l  = (const float*)d_in[6];
  const float* v1g1 = (const float*)d_in[7];
  const float* v1g2 = (const float*)d_in[8];
  const float* v2l  = (const float*)d_in[9];
  const float* v2g  = (const float*)d_in[10];
  float* out = (float*)d_out;

  unsigned short* xt = (unsigned short*)d_ws;      // 17,842,176 bf16
  float* partials = (float*)(xt + 17842176);       // 131,072 f32
  unsigned short* wpack = (unsigned short*)(partials + 131072);  // 1,179,648 bf16

  prep_kernel<<<4096, 256, 0, stream>>>(x, xt, partials);
  glgf_pack<<<128, 256, 0, stream>>>(partials, w1l, w1g1, w1g2, w2l, w2g,
                                     v1l, v1g1, v1g2, v2l, v2g, wpack);
  conv_kernel<<<1024, 256, 0, stream>>>(wpack, xt, out);
}